// Round 5
// baseline (184.741 us; speedup 1.0000x reference)
//
#include <hip/hip_runtime.h>

#define W      512
#define IMG    (512 * 512)
#define NB     16
#define NPIX   (NB * IMG)
#define BLOCK  256
#define NEDT   1024    // 16 img * 8 stripes * 8 seg-quads (each wave: 16 rows)
#define NLOSS  256     // 16 img * 8 col-groups * 2 row-halves
#define NTOT   (NEDT + NLOSS)

struct WS {
    unsigned int done;              // memset to 0 each launch (4 bytes)
    unsigned int ebmax[NEDT * 4];   // per-EDT-wave max d^2 (plain stores)
    float rows[NB * W];             // w_edt[b, h=b, :]
    float colpart[NLOSS][64];       // per-loss-block column sums of t*d^2
    float lpart[NLOSS][8];          // per-loss-block {pt, pp, st, C, A}
};

// Single fused kernel. Blocks [0,NEDT): exact EDT via ballot-bit windows and a
// 7-deep register pipeline (D capped at 5 — exact for best<=16, fallback else).
// Blocks [NEDT,NTOT): EDT-independent loss sums, column-complete per block.
// Last block to finish (device-scope counter) runs the finalize.
__global__ __launch_bounds__(BLOCK) void fused_kernel(const float* __restrict__ inp,
                                                      const float* __restrict__ tgt,
                                                      WS* __restrict__ ws,
                                                      float* __restrict__ out) {
    __shared__ float csm[4][64];     // loss column partials across the 4 waves
    __shared__ float sredf[4][8];    // loss scalar cross-wave reduce
    __shared__ float fvmax[16], Aimg[16];
    __shared__ double shd[4][6];
    __shared__ int   slast;

    int blk  = blockIdx.x;
    int tid  = threadIdx.x;
    int wv   = tid >> 6, lane = tid & 63;

    if (blk < NEDT) {
        // ================= EDT role =================
        int eid    = blk;
        int b      = eid >> 6;
        int stripe = (eid >> 3) & 7;
        int segq   = eid & 7;
        int seg    = segq * 4 + wv;          // 32 segments of 16 rows
        int r0     = seg << 4;
        int c0     = stripe << 6;
        const float* img = tgt + (size_t)b * IMG;

        int D0 = 5, D1 = 5, D2 = 5, D3 = 5, D4 = 5, D5 = 5, D6 = 5;
        unsigned int bmax = 0;
        for (int rr = r0 - 3; rr <= r0 + 18; ++rr) {
            bool inrow = (rr >= 0) & (rr < W);
            const float* rowp = img + (rr << 9);
            float v = 1.0f;
            if (inrow) v = rowp[c0 + lane];
            unsigned long long m = __ballot(v == 0.0f);
            float e = 1.0f;
            if (inrow && lane < 8) {
                int ec = (lane < 4) ? (c0 - 4 + lane) : (c0 + 60 + lane);
                if (ec >= 0 && ec < W) e = rowp[ec];
            }
            unsigned long long eb = __ballot(e == 0.0f);
            // 72-bit window [hi:lo], bit k <-> column c0+k-4
            unsigned long long lo = (m << 4) | (eb & 0xFULL);
            unsigned long long hi = (m >> 60) | (((eb >> 4) & 0xFULL) << 4);
            unsigned int win = (unsigned int)(((lo >> lane) |
                               (lane ? (hi << (64 - lane)) : 0ULL)) & 0x1FFULL);
            unsigned int rb = (win >> 4);            // bit0 = self .. bit4 = +4
            int dr = __builtin_ctz(rb | 0x20u);      // 0..5
            unsigned int lb = win & 0xFu;            // bit3 = -1 .. bit0 = -4
            int dl = lb ? (__builtin_clz(lb) - 27) : 5;
            int Dn = min(dr, dl);
            D0 = D1; D1 = D2; D2 = D3; D3 = D4; D4 = D5; D5 = D6; D6 = Dn;
            int er = rr - 3;
            if (er >= r0) {
                int m1 = min(D2, D4), m2 = min(D1, D5), m3 = min(D0, D6);
                int best = min(min(D3 * D3, 1 + m1 * m1),
                               min(4 + m2 * m2, 9 + m3 * m3));
                if (best > 16) {   // exactness fallback, P ~ 2^-47 per px
                    int y = c0 + lane;
                    int nb = 100000000;   // reference BIG if image has no zeros
                    for (int gh = 0; gh < W; ++gh) {
                        int dhh = gh - er, dh2 = dhh * dhh;
                        if (dh2 >= nb) continue;
                        const float* rp = img + (gh << 9);
                        for (int yy = 0; yy < W; ++yy)
                            if (rp[yy] == 0.0f) {
                                int dx = yy - y;
                                nb = min(nb, dh2 + dx * dx);
                            }
                    }
                    best = nb;
                }
                if (er == b) ws->rows[(b << 9) + c0 + lane] = sqrtf((float)best);
                bmax = max(bmax, (unsigned int)best);
            }
        }
        #pragma unroll
        for (int o = 32; o > 0; o >>= 1)
            bmax = max(bmax, (unsigned int)__shfl_down((int)bmax, o));
        if (lane == 0) ws->ebmax[(eid << 2) + wv] = bmax;
    } else {
        // ================= loss role =================
        int lid  = blk - NEDT;
        int b    = lid >> 4;
        int cg   = (lid >> 1) & 7;
        int half = lid & 1;
        int c    = (cg << 6) + lane;
        const float* ip = inp + (size_t)b * IMG;
        const float* tp = tgt + (size_t)b * IMG;
        float cs = 0.f, pt = 0.f, pp = 0.f, st = 0.f, Cc = 0.f, Aa = 0.f;
        int rbase = (half << 8) + wv;
        #pragma unroll 4
        for (int k = 0; k < 64; ++k) {
            int off = ((rbase + (k << 2)) << 9) + c;
            float x = ip[off], t = tp[off];
            float d = x - t, dd = d * d;
            Cc += dd;
            float td2 = t * dd; Aa += td2; cs += td2;
            float p = 1.0f / (1.0f + __expf(-x));
            pt += p * t; pp += p; st += t;
        }
        csm[wv][lane] = cs;
        #pragma unroll
        for (int o = 32; o > 0; o >>= 1) {
            pt += __shfl_down(pt, o); pp += __shfl_down(pp, o);
            st += __shfl_down(st, o); Cc += __shfl_down(Cc, o);
            Aa += __shfl_down(Aa, o);
        }
        if (lane == 0) { sredf[wv][0] = pt; sredf[wv][1] = pp; sredf[wv][2] = st;
                         sredf[wv][3] = Cc; sredf[wv][4] = Aa; }
        __syncthreads();
        if (tid < 64)
            ws->colpart[lid][tid] = csm[0][tid] + csm[1][tid] + csm[2][tid] + csm[3][tid];
        if (tid == 0) {
            float a0 = 0, a1 = 0, a2 = 0, a3 = 0, a4 = 0;
            #pragma unroll
            for (int i = 0; i < 4; ++i) {
                a0 += sredf[i][0]; a1 += sredf[i][1]; a2 += sredf[i][2];
                a3 += sredf[i][3]; a4 += sredf[i][4];
            }
            float* pr = ws->lpart[lid];
            pr[0] = a0; pr[1] = a1; pr[2] = a2; pr[3] = a3; pr[4] = a4;
        }
    }

    // ============ last-block finalize (device-scope handshake) ============
    __threadfence();
    __syncthreads();
    if (tid == 0)
        slast = (atomicAdd(&ws->done, 1u) == (unsigned int)(NTOT - 1));
    __syncthreads();
    if (!slast) return;
    __threadfence();   // acquire

    // per-image vmax (16 threads/image over 256 ebmax slots) and A_b
    int bimg = tid >> 4, j = tid & 15;
    unsigned int mx = 0;
    #pragma unroll
    for (int k = 0; k < 16; ++k)
        mx = max(mx, ws->ebmax[(bimg << 8) + j + (k << 4)]);
    float a4 = ws->lpart[(bimg << 4) + j][4];
    #pragma unroll
    for (int o = 8; o > 0; o >>= 1) {
        mx = max(mx, (unsigned int)__shfl_down((int)mx, o));
        a4 += __shfl_down(a4, o);
    }
    if (j == 0) { fvmax[bimg] = sqrtf((float)mx); Aimg[bimg] = a4; }

    // global scalars: one lpart row per thread (NLOSS == BLOCK)
    const float* pr = ws->lpart[tid];
    double pt = pr[0], pp = pr[1], st = pr[2], C = pr[3];
    __syncthreads();

    // dot(rows, Scol) over 16*512
    double dot = 0.0;
    for (int i = tid; i < NB * W; i += BLOCK) {
        int bb = i >> 9, c = i & 511;
        int lidb = (bb << 4) + (((c >> 6) & 7) << 1);
        float scol = ws->colpart[lidb][c & 63] + ws->colpart[lidb + 1][c & 63];
        dot += (double)ws->rows[i] * (double)scol;
    }
    double vA = (tid < 16) ? (double)fvmax[tid] * (double)Aimg[tid] : 0.0;

    #pragma unroll
    for (int o = 32; o > 0; o >>= 1) {
        pt += __shfl_down(pt, o); pp += __shfl_down(pp, o);
        st += __shfl_down(st, o); C  += __shfl_down(C, o);
        dot += __shfl_down(dot, o); vA += __shfl_down(vA, o);
    }
    if (lane == 0) { shd[wv][0] = pt; shd[wv][1] = pp; shd[wv][2] = st;
                     shd[wv][3] = C;  shd[wv][4] = dot; shd[wv][5] = vA; }
    __syncthreads();
    if (tid == 0) {
        double a0 = 0, a1 = 0, a2 = 0, a3 = 0, a5 = 0, a6 = 0;
        #pragma unroll
        for (int i = 0; i < 4; ++i) {
            a0 += shd[i][0]; a1 += shd[i][1]; a2 += shd[i][2];
            a3 += shd[i][3]; a5 += shd[i][4]; a6 += shd[i][5];
        }
        double wsum = a6 - a5 + 0.001 * a3;   // v·A - rows·Scol + eps·C
        out[0] = (float)(0.6 * (wsum / (double)NPIX));
        out[1] = (float)(1.0 - (2.0 * a0 + 1e-6) / (a1 + a2 + 1e-6));
    }
}

extern "C" void kernel_launch(void* const* d_in, const int* in_sizes, int n_in,
                              void* d_out, int out_size, void* d_ws, size_t ws_size,
                              hipStream_t stream) {
    const float* inp = (const float*)d_in[0];
    const float* tgt = (const float*)d_in[1];
    float* out = (float*)d_out;
    WS* ws = (WS*)d_ws;

    hipMemsetAsync(&ws->done, 0, sizeof(unsigned int), stream);
    fused_kernel<<<NTOT, BLOCK, 0, stream>>>(inp, tgt, ws, out);
}

// Round 6
// 131.505 us; speedup vs baseline: 1.4048x; 1.4048x over previous
//
#include <hip/hip_runtime.h>

#define W      512
#define IMG    (512 * 512)
#define NB     16
#define NPIX   (NB * IMG)
#define BLOCK  256
#define NEDT   256     // 16 img x 16 row-groups (32 rows/block; each wave: 8 rows)
#define NLOSS  256     // 16 img x 8 col-groups x 2 row-halves
#define NTOT   (NEDT + NLOSS)

struct WS {
    unsigned int done;              // memset 0 each launch (4 bytes)
    unsigned int ebmax[NEDT * 4];   // per-EDT-wave max d^2 (plain stores)
    float rows[NB * W];             // w_edt[b, h=b, :]
    float colpart[NLOSS][64];       // per-loss-block column sums of t*d^2
    float lpart[NLOSS][8];          // per-loss-block {pt, pp, st, C, A}
};

// Exactness fallback (P ~ 2^-47 per pixel) — one copy, never inlined 64x.
__device__ __noinline__ int brute_force(const float* __restrict__ img, int h, int y) {
    int nb = 100000000;   // reference BIG when image has no zeros
    for (int gh = 0; gh < W; ++gh) {
        int dhh = gh - h, dh2 = dhh * dhh;
        if (dh2 >= nb) continue;
        const float* rp = img + (gh << 9);
        for (int yy = 0; yy < W; ++yy)
            if (rp[yy] == 0.0f) { int dx = yy - y; nb = min(nb, dh2 + dx * dx); }
    }
    return nb;
}

__global__ __launch_bounds__(BLOCK) void fused_kernel(const float* __restrict__ inp,
                                                      const float* __restrict__ tgt,
                                                      WS* __restrict__ ws,
                                                      float* __restrict__ out) {
    __shared__ float csm[4][64];
    __shared__ float sredf[4][8];
    __shared__ float fvmax[16], Aimg[16];
    __shared__ double shd[4][6];
    __shared__ int   slast;

    int blk = blockIdx.x, tid = threadIdx.x;
    int wv = tid >> 6, lane = tid & 63;

    if (blk < NEDT) {
        // ================= EDT role: full-row ballot pipeline =================
        int b   = blk >> 4;
        int grp = blk & 15;
        int r0  = (grp << 5) + (wv << 3);    // wave's first output row
        const float* img = tgt + (size_t)b * IMG;

        float buf[4][8];                     // 3-row lookahead (constant-indexed)
        unsigned int P0 = 0, P1 = 0, P2 = 0, P3 = 0, P4 = 0, P5 = 0, P6 = 0;
        unsigned int bmax = 0;

        auto loadrow = [&](int i) {
            int rr = r0 - 3 + i;
            float* d = buf[i & 3];
            if (rr >= 0 && rr < W) {         // wave-uniform
                const float* rp = img + (rr << 9);
                #pragma unroll
                for (int k = 0; k < 8; ++k) d[k] = rp[(k << 6) + lane];
            } else {
                #pragma unroll
                for (int k = 0; k < 8; ++k) d[k] = 1.0f;
            }
        };

        loadrow(0); loadrow(1); loadrow(2);
        #pragma unroll
        for (int i = 0; i < 14; ++i) {
            if (i + 3 < 14) loadrow(i + 3);
            const float* v = buf[i & 3];
            unsigned long long B[8];
            #pragma unroll
            for (int k = 0; k < 8; ++k) B[k] = __ballot(v[k] == 0.0f);
            // row profile D (cap 5), 4-bit packed x8 words; window math is
            // SGPR u64 assembling + per-lane shift/ctz — branch-free.
            unsigned int Dn = 0;
            #pragma unroll
            for (int k = 0; k < 8; ++k) {
                unsigned long long Bm = k ? B[k - 1] : 0ULL;
                unsigned long long Bp = (k < 7) ? B[k + 1] : 0ULL;
                unsigned long long lo = (B[k] << 4) | (Bm >> 60);
                unsigned long long hi = (B[k] >> 60) | (Bp << 4);
                unsigned int win = (unsigned int)(((lo >> lane) |
                                   ((hi << (63 - lane)) << 1)) & 0x1FFULL);
                int dr = __builtin_ctz((win >> 4) | 0x20u);         // 0..5
                unsigned int lb = win & 0xFu;                        // cols y-1..y-4
                int dl = lb ? (__builtin_clz(lb) - 27) : 5;
                Dn |= (unsigned int)min(dr, dl) << (k << 2);
            }
            P0 = P1; P1 = P2; P2 = P3; P3 = P4; P4 = P5; P5 = P6; P6 = Dn;
            if (i >= 6) {
                int er = r0 + i - 6;
                #pragma unroll
                for (int k = 0; k < 8; ++k) {
                    int sh = k << 2;
                    int d3 = (P3 >> sh) & 15;
                    int m1 = min((P2 >> sh) & 15, (P4 >> sh) & 15);
                    int m2 = min((P1 >> sh) & 15, (P5 >> sh) & 15);
                    int m3 = min((P0 >> sh) & 15, (P6 >> sh) & 15);
                    int best = min(min(d3 * d3, 1 + m1 * m1),
                                   min(4 + m2 * m2, 9 + m3 * m3));
                    if (best > 16) best = brute_force(img, er, (k << 6) + lane);
                    if (er == b) ws->rows[(b << 9) + (k << 6) + lane] = sqrtf((float)best);
                    bmax = max(bmax, (unsigned int)best);
                }
            }
        }
        #pragma unroll
        for (int o = 32; o > 0; o >>= 1)
            bmax = max(bmax, (unsigned int)__shfl_down((int)bmax, o));
        if (lane == 0) ws->ebmax[(blk << 2) + wv] = bmax;
    } else {
        // ================= loss role =================
        int lid  = blk - NEDT;
        int b    = lid >> 4;
        int cg   = (lid >> 1) & 7;
        int half = lid & 1;
        int c    = (cg << 6) + lane;
        const float* ip = inp + (size_t)b * IMG;
        const float* tp = tgt + (size_t)b * IMG;
        float cs = 0.f, pt = 0.f, pp = 0.f, st = 0.f, Cc = 0.f, Aa = 0.f;
        int rbase = (half << 8) + wv;
        #pragma unroll 8
        for (int k = 0; k < 64; ++k) {
            int off = ((rbase + (k << 2)) << 9) + c;
            float x = ip[off], t = tp[off];
            float d = x - t, dd = d * d;
            Cc += dd;
            float td2 = t * dd; Aa += td2; cs += td2;
            float p = 1.0f / (1.0f + __expf(-x));
            pt += p * t; pp += p; st += t;
        }
        csm[wv][lane] = cs;
        #pragma unroll
        for (int o = 32; o > 0; o >>= 1) {
            pt += __shfl_down(pt, o); pp += __shfl_down(pp, o);
            st += __shfl_down(st, o); Cc += __shfl_down(Cc, o);
            Aa += __shfl_down(Aa, o);
        }
        if (lane == 0) { sredf[wv][0] = pt; sredf[wv][1] = pp; sredf[wv][2] = st;
                         sredf[wv][3] = Cc; sredf[wv][4] = Aa; }
        __syncthreads();
        if (tid < 64)
            ws->colpart[lid][tid] = csm[0][tid] + csm[1][tid] + csm[2][tid] + csm[3][tid];
        if (tid == 0) {
            float a0 = 0, a1 = 0, a2 = 0, a3 = 0, a4 = 0;
            #pragma unroll
            for (int i = 0; i < 4; ++i) {
                a0 += sredf[i][0]; a1 += sredf[i][1]; a2 += sredf[i][2];
                a3 += sredf[i][3]; a4 += sredf[i][4];
            }
            float* pr = ws->lpart[lid];
            pr[0] = a0; pr[1] = a1; pr[2] = a2; pr[3] = a3; pr[4] = a4;
        }
    }

    // ============ last-block finalize (device-scope handshake) ============
    __threadfence();
    __syncthreads();
    if (tid == 0)
        slast = (atomicAdd(&ws->done, 1u) == (unsigned int)(NTOT - 1));
    __syncthreads();
    if (!slast) return;
    __threadfence();   // acquire

    // per-image vmax (16 threads/image over 64 slots) and A_b (16 lpart rows)
    int bimg = tid >> 4, j = tid & 15;
    unsigned int mx = 0;
    #pragma unroll
    for (int k = 0; k < 4; ++k)
        mx = max(mx, ws->ebmax[(bimg << 6) + (j << 2) + k]);
    float a4 = ws->lpart[(bimg << 4) + j][4];
    #pragma unroll
    for (int o = 8; o > 0; o >>= 1) {
        mx = max(mx, (unsigned int)__shfl_down((int)mx, o));
        a4 += __shfl_down(a4, o);
    }
    if (j == 0) { fvmax[bimg] = sqrtf((float)mx); Aimg[bimg] = a4; }

    const float* pr = ws->lpart[tid];    // NLOSS == BLOCK
    double pt = pr[0], pp = pr[1], st = pr[2], C = pr[3];
    __syncthreads();

    double dot = 0.0;
    for (int i = tid; i < NB * W; i += BLOCK) {
        int bb = i >> 9, c = i & 511;
        int lidb = (bb << 4) + (((c >> 6) & 7) << 1);
        float scol = ws->colpart[lidb][c & 63] + ws->colpart[lidb + 1][c & 63];
        dot += (double)ws->rows[i] * (double)scol;
    }
    double vA = (tid < 16) ? (double)fvmax[tid] * (double)Aimg[tid] : 0.0;

    #pragma unroll
    for (int o = 32; o > 0; o >>= 1) {
        pt += __shfl_down(pt, o); pp += __shfl_down(pp, o);
        st += __shfl_down(st, o); C  += __shfl_down(C, o);
        dot += __shfl_down(dot, o); vA += __shfl_down(vA, o);
    }
    if (lane == 0) { shd[wv][0] = pt; shd[wv][1] = pp; shd[wv][2] = st;
                     shd[wv][3] = C;  shd[wv][4] = dot; shd[wv][5] = vA; }
    __syncthreads();
    if (tid == 0) {
        double a0 = 0, a1 = 0, a2 = 0, a3 = 0, a5 = 0, a6 = 0;
        #pragma unroll
        for (int i = 0; i < 4; ++i) {
            a0 += shd[i][0]; a1 += shd[i][1]; a2 += shd[i][2];
            a3 += shd[i][3]; a5 += shd[i][4]; a6 += shd[i][5];
        }
        double wsum = a6 - a5 + 0.001 * a3;   // v·A - rows·Scol + eps·C
        out[0] = (float)(0.6 * (wsum / (double)NPIX));
        out[1] = (float)(1.0 - (2.0 * a0 + 1e-6) / (a1 + a2 + 1e-6));
    }
}

extern "C" void kernel_launch(void* const* d_in, const int* in_sizes, int n_in,
                              void* d_out, int out_size, void* d_ws, size_t ws_size,
                              hipStream_t stream) {
    const float* inp = (const float*)d_in[0];
    const float* tgt = (const float*)d_in[1];
    float* out = (float*)d_out;
    WS* ws = (WS*)d_ws;

    hipMemsetAsync(&ws->done, 0, sizeof(unsigned int), stream);
    fused_kernel<<<NTOT, BLOCK, 0, stream>>>(inp, tgt, ws, out);
}